// Round 1
// baseline (1003.907 us; speedup 1.0000x reference)
//
#include <hip/hip_runtime.h>
#include <cstdint>
#include <cstddef>

// ---------------------------------------------------------------------------
// Problem constants
// ---------------------------------------------------------------------------
constexpr int NB = 256;   // batch
constexpr int NC = 512;   // c_length
constexpr int NL = 16;    // lattice side
constexpr int NFS = 15;   // neighborhood size
constexpr int NGATE4 = 4 * NC; // 2048

// JAX PRNG mode: 1 = threefry_partitionable (JAX >= 0.4.36 default), 0 = legacy
#define PARTITIONABLE 1

// ---------------------------------------------------------------------------
// Threefry2x32-20 (JAX-compatible), usable at compile time and on device
// ---------------------------------------------------------------------------
struct TFOut { uint32_t a, b; };

__host__ __device__ constexpr uint32_t rotl32(uint32_t x, int d) {
  return (x << d) | (x >> (32 - d));
}

__host__ __device__ constexpr TFOut tf2x32(uint32_t k0, uint32_t k1,
                                           uint32_t x0, uint32_t x1) {
  uint32_t k2 = k0 ^ k1 ^ 0x1BD11BDAu;
  x0 += k0; x1 += k1;
  const int R0[4] = {13, 15, 26, 6};
  const int R1[4] = {17, 29, 16, 24};
  for (int i = 0; i < 4; i++) { x0 += x1; x1 = rotl32(x1, R0[i]); x1 ^= x0; }
  x0 += k1; x1 += k2 + 1u;
  for (int i = 0; i < 4; i++) { x0 += x1; x1 = rotl32(x1, R1[i]); x1 ^= x0; }
  x0 += k2; x1 += k0 + 2u;
  for (int i = 0; i < 4; i++) { x0 += x1; x1 = rotl32(x1, R0[i]); x1 ^= x0; }
  x0 += k0; x1 += k1 + 3u;
  for (int i = 0; i < 4; i++) { x0 += x1; x1 = rotl32(x1, R1[i]); x1 ^= x0; }
  x0 += k1; x1 += k2 + 4u;
  for (int i = 0; i < 4; i++) { x0 += x1; x1 = rotl32(x1, R0[i]); x1 ^= x0; }
  x0 += k2; x1 += k0 + 5u;
  return TFOut{x0, x1};
}

// 144 sub-keys from the split chain starting at jax.random.key(1234),
// computed at COMPILE TIME (the chain is serial; no point doing it on-GPU).
struct SubKeys { uint32_t v[288]; };

constexpr SubKeys make_subkeys() {
  SubKeys s{};
  uint32_t k0 = 0u, k1 = 1234u;
  for (int t = 0; t < 144; t++) {
#if PARTITIONABLE
    TFOut nk = tf2x32(k0, k1, 0u, 0u);   // new key
    TFOut sk = tf2x32(k0, k1, 0u, 1u);   // subkey
    s.v[2 * t] = sk.a; s.v[2 * t + 1] = sk.b;
    k0 = nk.a; k1 = nk.b;
#else
    TFOut p0 = tf2x32(k0, k1, 0u, 2u);
    TFOut p1 = tf2x32(k0, k1, 1u, 3u);
    s.v[2 * t] = p0.b; s.v[2 * t + 1] = p1.b;   // sub = second row
    k0 = p0.a; k1 = p1.a;                       // key = first row
#endif
  }
  return s;
}

__constant__ SubKeys SUBKEYS = make_subkeys();

// JAX uniform->gumbel: u = max(tiny, bitcast(bits>>9 | 0x3f800000) - 1),
// g = -log(-log(u)), all effectively fp32.
__device__ __forceinline__ float gumbel_from_bits(uint32_t bits) {
  uint32_t ub = (bits >> 9) | 0x3f800000u;
  float f = __uint_as_float(ub) - 1.0f;
  float u = (f == 0.0f) ? 1.17549435e-38f : f;
  float inner = logf(u);        // negative
  float outer = logf(-inner);
  return -outer;
}

// ---------------------------------------------------------------------------
// Kernel 0: init workspace + outputs (d_out/d_ws are poisoned every launch)
// grid covers 2*4*NB*NC = 1,048,576 threads exactly
// ---------------------------------------------------------------------------
__global__ __launch_bounds__(256) void setup_kernel(
    const float* __restrict__ u_in, const int* __restrict__ v_in,
    float* __restrict__ h0buf, float* __restrict__ cbuf,
    float* __restrict__ u_cur, int* __restrict__ v_cur,
    float* __restrict__ out_soft, float* __restrict__ out_u,
    float* __restrict__ out_v) {
  int idx = blockIdx.x * 256 + threadIdx.x;
  h0buf[idx] = 0.0f;                       // both parities of h
  if (idx < 4 * NB * NC) cbuf[idx] = 0.0f; // lstm cell state
  if (idx < NB * NL * NL) {
    float uv = u_in[idx];
    int vv = v_in[idx];
    u_cur[idx] = uv;
    v_cur[idx] = vv;
    out_u[idx] = uv;
    out_v[idx] = (float)vv;
  }
  if (idx < NB * NL * NL * 2) out_soft[idx] = 0.0f;
}

// ---------------------------------------------------------------------------
// Kernel 1: precompute WD[n][c] = W1 · (emb[n,1]-emb[n,0])  (n=0..14)
//           A0[c]   = W1 · (Σ_n emb[n,0]) + b1
// one block per n (block 15 = A0); double accumulation
// ---------------------------------------------------------------------------
__global__ __launch_bounds__(256) void wd_kernel(
    const float* __restrict__ emb, const float* __restrict__ w1,
    const float* __restrict__ b1, float* __restrict__ WD,
    float* __restrict__ A0v) {
  __shared__ double dvec[NC];
  int n = blockIdx.x, tid = threadIdx.x;
  for (int k = tid; k < NC; k += 256) {
    if (n < NFS) {
      dvec[k] = (double)emb[(n * 2 + 1) * NC + k] - (double)emb[(n * 2) * NC + k];
    } else {
      double s = 0.0;
      for (int nn = 0; nn < NFS; nn++) s += (double)emb[(nn * 2) * NC + k];
      dvec[k] = s;
    }
  }
  __syncthreads();
  for (int c = tid; c < NC; c += 256) {
    double acc = 0.0;
    const float* wrow = w1 + (size_t)c * NC;
    for (int k = 0; k < NC; k++) acc += dvec[k] * (double)wrow[k];
    if (n < NFS) WD[n * NC + c] = (float)acc;
    else         A0v[c] = (float)(acc + (double)b1[c]);
  }
}

// ---------------------------------------------------------------------------
// Kernel 2: one LSTM "sector event": for s in 0..2 advance memj[s] (layer 0).
//   g = uv@wih^T + bih + h@whh^T + bhh ; gate update -> c (in place), h (ping-pong)
// uv ∈ {0,1}: columns col0..col0+3 of u_cur. Tile: 64 rows x 16 cols x 4 gates.
// grid = 3(s) * 4(bt) * 32(ct) = 384 blocks, 256 threads.
// ---------------------------------------------------------------------------
__global__ __launch_bounds__(256) void lstm_event_kernel(
    const float* __restrict__ u_cur, const float* __restrict__ whh,
    const float* __restrict__ wih, const float* __restrict__ bih,
    const float* __restrict__ bhh, const float* __restrict__ h_in,
    float* __restrict__ h_out, float* __restrict__ cbuf, int col0) {
  int bx = blockIdx.x;
  int s = bx >> 7;
  int bt = (bx >> 5) & 3;
  int ct = bx & 31;
  int tid = threadIdx.x, tn = tid & 15, tb = tid >> 4;

  __shared__ float hs[64][36];   // 64 rows x 32 k (pad 36: 16B-aligned, 2-way max)
  __shared__ float wt[64][36];   // 64 (col,gate) x 32 k
  __shared__ float uvs[64][16];

  for (int idx = tid; idx < 1024; idx += 256) {
    int row = idx >> 4, nn = idx & 15;
    int b = bt * 64 + row;
    uvs[row][nn] = u_cur[b * 256 + (s * 4 + (nn >> 2)) * 16 + col0 + (nn & 3)];
  }

  float acc[4][4] = {};
  const float* hbase = h_in + ((size_t)s * NB + bt * 64) * NC;

  for (int k0 = 0; k0 < NC; k0 += 32) {
    __syncthreads();
    for (int t = 0; t < 2; t++) {
      int idx = tid + t * 256;            // [0,512)
      int row = idx >> 3, kk4 = idx & 7;
      *(float4*)&hs[row][kk4 * 4] =
          *(const float4*)(hbase + (size_t)row * NC + k0 + kk4 * 4);
      int wrow = ((row >> 4) * NC) + ct * 16 + (row & 15); // gate*512 + col
      *(float4*)&wt[row][kk4 * 4] =
          *(const float4*)(whh + (size_t)wrow * NC + k0 + kk4 * 4);
    }
    __syncthreads();
#pragma unroll
    for (int kk4 = 0; kk4 < 8; kk4++) {
      float4 hv[4], wv[4];
#pragma unroll
      for (int i = 0; i < 4; i++) hv[i] = *(float4*)&hs[tb * 4 + i][kk4 * 4];
#pragma unroll
      for (int g = 0; g < 4; g++) wv[g] = *(float4*)&wt[tn + 16 * g][kk4 * 4];
#pragma unroll
      for (int i = 0; i < 4; i++)
#pragma unroll
        for (int g = 0; g < 4; g++)
          acc[i][g] += hv[i].x * wv[g].x + hv[i].y * wv[g].y +
                       hv[i].z * wv[g].z + hv[i].w * wv[g].w;
    }
  }

  int c = ct * 16 + tn;
#pragma unroll
  for (int i = 0; i < 4; i++) {
    int row = tb * 4 + i, b = bt * 64 + row;
    float gv[4];
#pragma unroll
    for (int g = 0; g < 4; g++) {
      int nidx = g * NC + c;
      float extra = bih[nidx] + bhh[nidx];
      const float* wrow = wih + (size_t)nidx * 16;
#pragma unroll
      for (int nn = 0; nn < 16; nn++) extra += uvs[row][nn] * wrow[nn];
      gv[g] = acc[i][g] + extra;
    }
    size_t off = ((size_t)s * NB + b) * NC + c;
    float c_old = cbuf[off];
    float sig_i = 1.0f / (1.0f + expf(-gv[0]));
    float sig_f = 1.0f / (1.0f + expf(-gv[1]));
    float tg    = tanhf(gv[2]);
    float sig_o = 1.0f / (1.0f + expf(-gv[3]));
    float cn = sig_f * c_old + sig_i * tg;
    float hn = sig_o * tanhf(cn);
    cbuf[off] = cn;
    h_out[off] = hn;
  }
}

// ---------------------------------------------------------------------------
// Kernel 3: Hpart[ks][b][c] partial of H = W1 · h0 (h0 = memj[i] layer-0 h).
// grid = 8(ks,K=64 each) * 4(bt) * 8(ct) = 256 blocks, 256 threads.
// ---------------------------------------------------------------------------
__global__ __launch_bounds__(256) void w1h0_kernel(
    const float* __restrict__ h_in,   // [NB][NC] slice for (parity, s=i)
    const float* __restrict__ w1, float* __restrict__ Hpart) {
  int bx = blockIdx.x;
  int ks = bx >> 5;
  int bt = (bx >> 3) & 3;
  int ct = bx & 7;
  int tid = threadIdx.x, tn = tid & 15, tb = tid >> 4;

  __shared__ float hs[64][36];
  __shared__ float wt[64][36];
  float acc[4][4] = {};
  const float* hbase = h_in + (size_t)(bt * 64) * NC;

  for (int kc = 0; kc < 2; kc++) {
    int k0 = ks * 64 + kc * 32;
    __syncthreads();
    for (int t = 0; t < 2; t++) {
      int idx = tid + t * 256;
      int row = idx >> 3, kk4 = idx & 7;
      *(float4*)&hs[row][kk4 * 4] =
          *(const float4*)(hbase + (size_t)row * NC + k0 + kk4 * 4);
      int wrow = ct * 64 + row;
      *(float4*)&wt[row][kk4 * 4] =
          *(const float4*)(w1 + (size_t)wrow * NC + k0 + kk4 * 4);
    }
    __syncthreads();
#pragma unroll
    for (int kk4 = 0; kk4 < 8; kk4++) {
      float4 hv[4], wv[4];
#pragma unroll
      for (int i = 0; i < 4; i++) hv[i] = *(float4*)&hs[tb * 4 + i][kk4 * 4];
#pragma unroll
      for (int j = 0; j < 4; j++) wv[j] = *(float4*)&wt[tn + 16 * j][kk4 * 4];
#pragma unroll
      for (int i = 0; i < 4; i++)
#pragma unroll
        for (int j = 0; j < 4; j++)
          acc[i][j] += hv[i].x * wv[j].x + hv[i].y * wv[j].y +
                       hv[i].z * wv[j].z + hv[i].w * wv[j].w;
    }
  }
#pragma unroll
  for (int i = 0; i < 4; i++) {
    int b = bt * 64 + tb * 4 + i;
#pragma unroll
    for (int j = 0; j < 4; j++) {
      int cidx = ct * 64 + tn + 16 * j;
      Hpart[((size_t)ks * NB + b) * NC + cidx] = acc[i][j];
    }
  }
}

// ---------------------------------------------------------------------------
// Kernel 4: one 16-pixel autoregressive block for sector (si,sj).
// One workgroup (64 threads = 1 wave) per batch row; sequential over 16 pixels.
//   pre = A0 + H[b] + Σ_{n: p_n=1} WD[n] ; z = relu(pre)
//   logits = log_softmax(z@W2^T + b2) ; gumbel-argmax sample; write back v/u.
// ---------------------------------------------------------------------------
__global__ __launch_bounds__(64) void pixel_kernel(
    const float* __restrict__ WD, const float* __restrict__ A0v,
    const float* __restrict__ Hpart, const float* __restrict__ w2,
    const float* __restrict__ b2, float* __restrict__ u_cur,
    int* __restrict__ v_cur, float* __restrict__ out_soft,
    float* __restrict__ out_u, float* __restrict__ out_v,
    int si, int sj, int t_base) {
  int b = blockIdx.x, lane = threadIdx.x;
  __shared__ int vwin[49];        // 7x7 window rows si+1..si+7, cols sj+1..sj+7
  __shared__ float gum[16][2];    // precomputed gumbel noise for 16 pixels

  if (lane < 49)
    vwin[lane] = v_cur[b * 256 + (si + 1 + lane / 7) * 16 + (sj + 1 + lane % 7)];

  if (lane < 32) {
    int pix = lane >> 1, q = lane & 1;
    int t = t_base + pix;
    uint32_t sk0 = SUBKEYS.v[2 * t], sk1 = SUBKEYS.v[2 * t + 1];
    uint32_t bits;
#if PARTITIONABLE
    TFOut o = tf2x32(sk0, sk1, 0u, (uint32_t)(2 * b + q));
    bits = o.a ^ o.b;
#else
    uint32_t f = (uint32_t)(2 * b + q);
    if (f < 256u) { TFOut o = tf2x32(sk0, sk1, f, f + 256u); bits = o.a; }
    else          { TFOut o = tf2x32(sk0, sk1, f - 256u, f); bits = o.b; }
#endif
    gum[pix][q] = gumbel_from_bits(bits);
  }

  float base[8];
#pragma unroll
  for (int r = 0; r < 8; r++) {
    int c = lane + 64 * r;
    float v = A0v[c];
#pragma unroll
    for (int ks = 0; ks < 8; ks++) v += Hpart[((size_t)ks * NB + b) * NC + c];
    base[r] = v;
  }
  __syncthreads();

  for (int ii = 0; ii < 4; ii++) {
    for (int jj = 0; jj < 4; jj++) {
      float acc[8];
#pragma unroll
      for (int r = 0; r < 8; r++) acc[r] = base[r];
#pragma unroll
      for (int n = 0; n < NFS; n++) {
        int p = vwin[(ii + n / 4) * 7 + (jj + n % 4)];  // wave-uniform
        if (p) {
#pragma unroll
          for (int r = 0; r < 8; r++) acc[r] += WD[n * NC + lane + 64 * r];
        }
      }
      double d0 = 0.0, d1 = 0.0;
#pragma unroll
      for (int r = 0; r < 8; r++) {
        int c = lane + 64 * r;
        float z = fmaxf(acc[r], 0.0f);
        d0 += (double)z * (double)w2[c];
        d1 += (double)z * (double)w2[NC + c];
      }
#pragma unroll
      for (int off = 32; off > 0; off >>= 1) {
        d0 += __shfl_xor(d0, off, 64);
        d1 += __shfl_xor(d1, off, 64);
      }
      float r0 = (float)(d0 + (double)b2[0]);
      float r1 = (float)(d1 + (double)b2[1]);
      float m = fmaxf(r0, r1);
      float s0 = r0 - m, s1 = r1 - m;
      float lse = logf(expf(s0) + expf(s1));
      float l0 = s0 - lse, l1 = s1 - lse;
      int pidx = ii * 4 + jj;
      float a0 = l0 + gum[pidx][0];
      float a1 = l1 + gum[pidx][1];
      int samp = (a1 > a0) ? 1 : 0;   // argmax, first index wins ties
      if (lane == 0) {
        int pr = si + ii + 4, pc = sj + jj + 4;
        size_t so = ((size_t)(b * 16 + pr) * 16 + pc) * 2;
        out_soft[so] = l0;
        out_soft[so + 1] = l1;
        int po = b * 256 + pr * 16 + pc;
        float fs = (float)samp;
        u_cur[po] = fs;
        v_cur[po] = samp;
        out_u[po] = fs;
        out_v[po] = fs;
        vwin[(ii + 3) * 7 + (jj + 3)] = samp;
      }
      __syncthreads();
    }
  }
}

// ---------------------------------------------------------------------------
// Host-side launch sequence (stream-ordered; no grid syncs needed because the
// computation is batch-independent and kernel boundaries carry the sequential
// dependency between the 9 pixel blocks and 8 LSTM sector events).
// ---------------------------------------------------------------------------
extern "C" void kernel_launch(void* const* d_in, const int* in_sizes, int n_in,
                              void* d_out, int out_size, void* d_ws,
                              size_t ws_size, hipStream_t stream) {
  (void)in_sizes; (void)n_in; (void)out_size; (void)ws_size;
  const float* u_in = (const float*)d_in[0];
  const int*   v_in = (const int*)d_in[1];
  const float* emb  = (const float*)d_in[2];
  const float* w1   = (const float*)d_in[3];
  const float* b1   = (const float*)d_in[4];
  const float* w2   = (const float*)d_in[5];
  const float* b2   = (const float*)d_in[6];
  const float* wih  = (const float*)d_in[7];
  const float* whh  = (const float*)d_in[8];
  const float* bih  = (const float*)d_in[9];
  const float* bhh  = (const float*)d_in[10];
  // layer-1 LSTM params (d_in[11..14]) are dead code — never read.

  float* ws = (float*)d_ws;
  const size_t HP = (size_t)4 * NB * NC;          // 524288: h parity stride
  float* h0buf = ws;                               // [2][4][NB][NC]
  float* cbuf  = h0buf + 2 * HP;                   // [4][NB][NC]
  float* Hpart = cbuf + HP;                        // [8][NB][NC]
  float* WDp   = Hpart + (size_t)8 * NB * NC;      // [15][NC]
  float* A0v   = WDp + NFS * NC;                   // [NC]
  float* u_cur = A0v + NC;                         // [NB][16][16]
  int*   v_cur = (int*)(u_cur + NB * NL * NL);     // [NB][16][16]

  float* out_soft = (float*)d_out;                 // [NB][16][16][2]
  float* out_u = out_soft + NB * NL * NL * 2;      // [NB][16][16]
  float* out_v = out_u + NB * NL * NL;             // [NB][16][16] (as float)

  setup_kernel<<<dim3(4096), dim3(256), 0, stream>>>(
      u_in, v_in, h0buf, cbuf, u_cur, v_cur, out_soft, out_u, out_v);
  wd_kernel<<<dim3(16), dim3(256), 0, stream>>>(emb, w1, b1, WDp, A0v);

  for (int k = 0; k < 9; k++) {
    if (k > 0) {
      int e = k - 1;
      int col0 = (e % 3 == 0) ? 4 : ((e % 3 == 1) ? 8 : 0);
      lstm_event_kernel<<<dim3(384), dim3(256), 0, stream>>>(
          u_cur, whh, wih, bih, bhh,
          h0buf + (size_t)(e & 1) * HP,
          h0buf + (size_t)((e & 1) ^ 1) * HP, cbuf, col0);
    }
    w1h0_kernel<<<dim3(256), dim3(256), 0, stream>>>(
        h0buf + (size_t)(k & 1) * HP + (size_t)(k / 3) * NB * NC, w1, Hpart);
    pixel_kernel<<<dim3(256), dim3(64), 0, stream>>>(
        WDp, A0v, Hpart, w2, b2, u_cur, v_cur, out_soft, out_u, out_v,
        (k / 3) * 4, (k % 3) * 4, k * 16);
  }
}

// Round 2
// 721.792 us; speedup vs baseline: 1.3909x; 1.3909x over previous
//
#include <hip/hip_runtime.h>
#include <cstdint>
#include <cstddef>

// ---------------------------------------------------------------------------
// Problem constants
// ---------------------------------------------------------------------------
constexpr int NB = 256;   // batch
constexpr int NC = 512;   // c_length
constexpr int NL = 16;    // lattice side
constexpr int NFS = 15;   // neighborhood size

#define PARTITIONABLE 1

// ---------------------------------------------------------------------------
// Threefry2x32-20 (JAX-compatible), usable at compile time and on device
// ---------------------------------------------------------------------------
struct TFOut { uint32_t a, b; };

__host__ __device__ constexpr uint32_t rotl32(uint32_t x, int d) {
  return (x << d) | (x >> (32 - d));
}

__host__ __device__ constexpr TFOut tf2x32(uint32_t k0, uint32_t k1,
                                           uint32_t x0, uint32_t x1) {
  uint32_t k2 = k0 ^ k1 ^ 0x1BD11BDAu;
  x0 += k0; x1 += k1;
  const int R0[4] = {13, 15, 26, 6};
  const int R1[4] = {17, 29, 16, 24};
  for (int i = 0; i < 4; i++) { x0 += x1; x1 = rotl32(x1, R0[i]); x1 ^= x0; }
  x0 += k1; x1 += k2 + 1u;
  for (int i = 0; i < 4; i++) { x0 += x1; x1 = rotl32(x1, R1[i]); x1 ^= x0; }
  x0 += k2; x1 += k0 + 2u;
  for (int i = 0; i < 4; i++) { x0 += x1; x1 = rotl32(x1, R0[i]); x1 ^= x0; }
  x0 += k0; x1 += k1 + 3u;
  for (int i = 0; i < 4; i++) { x0 += x1; x1 = rotl32(x1, R1[i]); x1 ^= x0; }
  x0 += k1; x1 += k2 + 4u;
  for (int i = 0; i < 4; i++) { x0 += x1; x1 = rotl32(x1, R0[i]); x1 ^= x0; }
  x0 += k2; x1 += k0 + 5u;
  return TFOut{x0, x1};
}

// 144 sub-keys from the split chain starting at jax.random.key(1234),
// computed at COMPILE TIME.
struct SubKeys { uint32_t v[288]; };

constexpr SubKeys make_subkeys() {
  SubKeys s{};
  uint32_t k0 = 0u, k1 = 1234u;
  for (int t = 0; t < 144; t++) {
#if PARTITIONABLE
    TFOut nk = tf2x32(k0, k1, 0u, 0u);   // new key
    TFOut sk = tf2x32(k0, k1, 0u, 1u);   // subkey
    s.v[2 * t] = sk.a; s.v[2 * t + 1] = sk.b;
    k0 = nk.a; k1 = nk.b;
#else
    TFOut p0 = tf2x32(k0, k1, 0u, 2u);
    TFOut p1 = tf2x32(k0, k1, 1u, 3u);
    s.v[2 * t] = p0.b; s.v[2 * t + 1] = p1.b;
    k0 = p0.a; k1 = p1.a;
#endif
  }
  return s;
}

__constant__ SubKeys SUBKEYS = make_subkeys();

__device__ __forceinline__ float gumbel_from_bits(uint32_t bits) {
  uint32_t ub = (bits >> 9) | 0x3f800000u;
  float f = __uint_as_float(ub) - 1.0f;
  float u = (f == 0.0f) ? 1.17549435e-38f : f;
  float inner = logf(u);
  float outer = logf(-inner);
  return -outer;
}

// ---------------------------------------------------------------------------
// Kernel 0: init workspace + outputs
// ---------------------------------------------------------------------------
__global__ __launch_bounds__(256) void setup_kernel(
    const float* __restrict__ u_in, const int* __restrict__ v_in,
    float* __restrict__ h0buf, float* __restrict__ cbuf,
    float* __restrict__ u_cur, int* __restrict__ v_cur,
    float* __restrict__ out_soft, float* __restrict__ out_u,
    float* __restrict__ out_v) {
  int idx = blockIdx.x * 256 + threadIdx.x;
  h0buf[idx] = 0.0f;
  if (idx < 4 * NB * NC) cbuf[idx] = 0.0f;
  if (idx < NB * NL * NL) {
    float uv = u_in[idx];
    int vv = v_in[idx];
    u_cur[idx] = uv;
    v_cur[idx] = vv;
    out_u[idx] = uv;
    out_v[idx] = (float)vv;
  }
  if (idx < NB * NL * NL * 2) out_soft[idx] = 0.0f;
}

// ---------------------------------------------------------------------------
// Kernel 1: WD[n][c] = W1 · (emb[n,1]-emb[n,0]);  A0 = W1 · Σ emb[n,0] + b1
// ---------------------------------------------------------------------------
__global__ __launch_bounds__(256) void wd_kernel(
    const float* __restrict__ emb, const float* __restrict__ w1,
    const float* __restrict__ b1, float* __restrict__ WD,
    float* __restrict__ A0v) {
  __shared__ double dvec[NC];
  int n = blockIdx.x, tid = threadIdx.x;
  for (int k = tid; k < NC; k += 256) {
    if (n < NFS) {
      dvec[k] = (double)emb[(n * 2 + 1) * NC + k] - (double)emb[(n * 2) * NC + k];
    } else {
      double s = 0.0;
      for (int nn = 0; nn < NFS; nn++) s += (double)emb[(nn * 2) * NC + k];
      dvec[k] = s;
    }
  }
  __syncthreads();
  for (int c = tid; c < NC; c += 256) {
    double acc = 0.0;
    const float* wrow = w1 + (size_t)c * NC;
    for (int k = 0; k < NC; k++) acc += dvec[k] * (double)wrow[k];
    if (n < NFS) WD[n * NC + c] = (float)acc;
    else         A0v[c] = (float)(acc + (double)b1[c]);
  }
}

// ---------------------------------------------------------------------------
// Kernel 2: LSTM sector event (unchanged from round 1 — bit-identical h path)
// ---------------------------------------------------------------------------
__global__ __launch_bounds__(256) void lstm_event_kernel(
    const float* __restrict__ u_cur, const float* __restrict__ whh,
    const float* __restrict__ wih, const float* __restrict__ bih,
    const float* __restrict__ bhh, const float* __restrict__ h_in,
    float* __restrict__ h_out, float* __restrict__ cbuf, int col0) {
  int bx = blockIdx.x;
  int s = bx >> 7;
  int bt = (bx >> 5) & 3;
  int ct = bx & 31;
  int tid = threadIdx.x, tn = tid & 15, tb = tid >> 4;

  __shared__ float hs[64][36];
  __shared__ float wt[64][36];
  __shared__ float uvs[64][16];

  for (int idx = tid; idx < 1024; idx += 256) {
    int row = idx >> 4, nn = idx & 15;
    int b = bt * 64 + row;
    uvs[row][nn] = u_cur[b * 256 + (s * 4 + (nn >> 2)) * 16 + col0 + (nn & 3)];
  }

  float acc[4][4] = {};
  const float* hbase = h_in + ((size_t)s * NB + bt * 64) * NC;

  for (int k0 = 0; k0 < NC; k0 += 32) {
    __syncthreads();
    for (int t = 0; t < 2; t++) {
      int idx = tid + t * 256;
      int row = idx >> 3, kk4 = idx & 7;
      *(float4*)&hs[row][kk4 * 4] =
          *(const float4*)(hbase + (size_t)row * NC + k0 + kk4 * 4);
      int wrow = ((row >> 4) * NC) + ct * 16 + (row & 15);
      *(float4*)&wt[row][kk4 * 4] =
          *(const float4*)(whh + (size_t)wrow * NC + k0 + kk4 * 4);
    }
    __syncthreads();
#pragma unroll
    for (int kk4 = 0; kk4 < 8; kk4++) {
      float4 hv[4], wv[4];
#pragma unroll
      for (int i = 0; i < 4; i++) hv[i] = *(float4*)&hs[tb * 4 + i][kk4 * 4];
#pragma unroll
      for (int g = 0; g < 4; g++) wv[g] = *(float4*)&wt[tn + 16 * g][kk4 * 4];
#pragma unroll
      for (int i = 0; i < 4; i++)
#pragma unroll
        for (int g = 0; g < 4; g++)
          acc[i][g] += hv[i].x * wv[g].x + hv[i].y * wv[g].y +
                       hv[i].z * wv[g].z + hv[i].w * wv[g].w;
    }
  }

  int c = ct * 16 + tn;
#pragma unroll
  for (int i = 0; i < 4; i++) {
    int row = tb * 4 + i, b = bt * 64 + row;
    float gv[4];
#pragma unroll
    for (int g = 0; g < 4; g++) {
      int nidx = g * NC + c;
      float extra = bih[nidx] + bhh[nidx];
      const float* wrow = wih + (size_t)nidx * 16;
#pragma unroll
      for (int nn = 0; nn < 16; nn++) extra += uvs[row][nn] * wrow[nn];
      gv[g] = acc[i][g] + extra;
    }
    size_t off = ((size_t)s * NB + b) * NC + c;
    float c_old = cbuf[off];
    float sig_i = 1.0f / (1.0f + expf(-gv[0]));
    float sig_f = 1.0f / (1.0f + expf(-gv[1]));
    float tg    = tanhf(gv[2]);
    float sig_o = 1.0f / (1.0f + expf(-gv[3]));
    float cn = sig_f * c_old + sig_i * tg;
    float hn = sig_o * tanhf(cn);
    cbuf[off] = cn;
    h_out[off] = hn;
  }
}

// ---------------------------------------------------------------------------
// Kernel 3: Hpart[ks][b][c] partials of H = W1 · h0 (unchanged from round 1)
// ---------------------------------------------------------------------------
__global__ __launch_bounds__(256) void w1h0_kernel(
    const float* __restrict__ h_in,
    const float* __restrict__ w1, float* __restrict__ Hpart) {
  int bx = blockIdx.x;
  int ks = bx >> 5;
  int bt = (bx >> 3) & 3;
  int ct = bx & 7;
  int tid = threadIdx.x, tn = tid & 15, tb = tid >> 4;

  __shared__ float hs[64][36];
  __shared__ float wt[64][36];
  float acc[4][4] = {};
  const float* hbase = h_in + (size_t)(bt * 64) * NC;

  for (int kc = 0; kc < 2; kc++) {
    int k0 = ks * 64 + kc * 32;
    __syncthreads();
    for (int t = 0; t < 2; t++) {
      int idx = tid + t * 256;
      int row = idx >> 3, kk4 = idx & 7;
      *(float4*)&hs[row][kk4 * 4] =
          *(const float4*)(hbase + (size_t)row * NC + k0 + kk4 * 4);
      int wrow = ct * 64 + row;
      *(float4*)&wt[row][kk4 * 4] =
          *(const float4*)(w1 + (size_t)wrow * NC + k0 + kk4 * 4);
    }
    __syncthreads();
#pragma unroll
    for (int kk4 = 0; kk4 < 8; kk4++) {
      float4 hv[4], wv[4];
#pragma unroll
      for (int i = 0; i < 4; i++) hv[i] = *(float4*)&hs[tb * 4 + i][kk4 * 4];
#pragma unroll
      for (int j = 0; j < 4; j++) wv[j] = *(float4*)&wt[tn + 16 * j][kk4 * 4];
#pragma unroll
      for (int i = 0; i < 4; i++)
#pragma unroll
        for (int j = 0; j < 4; j++)
          acc[i][j] += hv[i].x * wv[j].x + hv[i].y * wv[j].y +
                       hv[i].z * wv[j].z + hv[i].w * wv[j].w;
    }
  }
#pragma unroll
  for (int i = 0; i < 4; i++) {
    int b = bt * 64 + tb * 4 + i;
#pragma unroll
    for (int j = 0; j < 4; j++) {
      int cidx = ct * 64 + tn + 16 * j;
      Hpart[((size_t)ks * NB + b) * NC + cidx] = acc[i][j];
    }
  }
}

// ---------------------------------------------------------------------------
// Kernel 4: 16-pixel autoregressive block — pure-register single-wave version.
// Window = uniform 49-bit register mask (ballot); WD/w2/base in VGPRs;
// arithmetic bit-identical to round 1 (fma(p,wd,acc) with p in {0,1},
// same double dot + same butterfly order).
// ---------------------------------------------------------------------------
__global__ __launch_bounds__(64) void pixel_kernel(
    const float* __restrict__ WD, const float* __restrict__ A0v,
    const float* __restrict__ Hpart, const float* __restrict__ w2,
    const float* __restrict__ b2, float* __restrict__ u_cur,
    int* __restrict__ v_cur, float* __restrict__ out_soft,
    float* __restrict__ out_u, float* __restrict__ out_v,
    int si, int sj, int t_base) {
  int b = blockIdx.x, lane = threadIdx.x;
  __shared__ float gum[32];

  // --- window bitmask: bit w (w<49) = v_cur[si+1+w/7][sj+1+w%7] != 0 ---
  int widx = (lane < 49) ? lane : 48;
  int vv = v_cur[b * 256 + (si + 1 + widx / 7) * 16 + (sj + 1 + widx % 7)];
  unsigned long long mask = __ballot((lane < 49) && (vv != 0));

  // --- gumbel noise for the 16 pixels (2 states each) ---
  if (lane < 32) {
    int t = t_base + (lane >> 1);
    uint32_t sk0 = SUBKEYS.v[2 * t], sk1 = SUBKEYS.v[2 * t + 1];
    uint32_t bits;
#if PARTITIONABLE
    TFOut o = tf2x32(sk0, sk1, 0u, (uint32_t)(2 * b + (lane & 1)));
    bits = o.a ^ o.b;
#else
    uint32_t f = (uint32_t)(2 * b + (lane & 1));
    if (f < 256u) { TFOut o = tf2x32(sk0, sk1, f, f + 256u); bits = o.a; }
    else          { TFOut o = tf2x32(sk0, sk1, f - 256u, f); bits = o.b; }
#endif
    gum[lane] = gumbel_from_bits(bits);
  }

  // --- preload everything into registers ---
  float wdreg[NFS][8];
#pragma unroll
  for (int n = 0; n < NFS; n++)
#pragma unroll
    for (int r = 0; r < 8; r++) wdreg[n][r] = WD[n * NC + lane + 64 * r];

  float w2r0[8], w2r1[8];
#pragma unroll
  for (int r = 0; r < 8; r++) {
    w2r0[r] = w2[lane + 64 * r];
    w2r1[r] = w2[NC + lane + 64 * r];
  }
  double b20 = (double)b2[0], b21 = (double)b2[1];

  float base[8];
#pragma unroll
  for (int r = 0; r < 8; r++) {
    int c = lane + 64 * r;
    float v = A0v[c];
#pragma unroll
    for (int ks = 0; ks < 8; ks++) v += Hpart[((size_t)ks * NB + b) * NC + c];
    base[r] = v;
  }
  __syncthreads();   // gum visible (one barrier total)

#pragma unroll 1
  for (int ii = 0; ii < 4; ii++) {
#pragma unroll 1
    for (int jj = 0; jj < 4; jj++) {
      int bofs = ii * 7 + jj;
      float acc[8];
#pragma unroll
      for (int r = 0; r < 8; r++) acc[r] = base[r];
#pragma unroll
      for (int n = 0; n < NFS; n++) {
        const int OFF = (n / 4) * 7 + (n % 4);
        float pf = (float)((unsigned)((mask >> (bofs + OFF)) & 1ull));
#pragma unroll
        for (int r = 0; r < 8; r++) acc[r] = fmaf(pf, wdreg[n][r], acc[r]);
      }
      double d0 = 0.0, d1 = 0.0;
#pragma unroll
      for (int r = 0; r < 8; r++) {
        float z = fmaxf(acc[r], 0.0f);
        d0 += (double)z * (double)w2r0[r];
        d1 += (double)z * (double)w2r1[r];
      }
#pragma unroll
      for (int off = 32; off > 0; off >>= 1) {
        d0 += __shfl_xor(d0, off, 64);
        d1 += __shfl_xor(d1, off, 64);
      }
      float r0 = (float)(d0 + b20);
      float r1 = (float)(d1 + b21);
      float m = fmaxf(r0, r1);
      float s0 = r0 - m, s1 = r1 - m;
      float lse = logf(expf(s0) + expf(s1));
      float l0 = s0 - lse, l1 = s1 - lse;
      int pidx = ii * 4 + jj;
      float a0 = l0 + gum[2 * pidx];
      float a1 = l1 + gum[2 * pidx + 1];
      int samp = (a1 > a0) ? 1 : 0;
      // update window mask (uniform on all lanes; clear then set target bit)
      int tbit = bofs + 24;
      mask = (mask & ~(1ull << tbit)) | ((unsigned long long)samp << tbit);
      if (lane == 0) {
        int pr = si + ii + 4, pc = sj + jj + 4;
        size_t so = ((size_t)(b * 16 + pr) * 16 + pc) * 2;
        out_soft[so] = l0;
        out_soft[so + 1] = l1;
        int po = b * 256 + pr * 16 + pc;
        float fs = (float)samp;
        u_cur[po] = fs;
        v_cur[po] = samp;
        out_u[po] = fs;
        out_v[po] = fs;
      }
    }
  }
}

// ---------------------------------------------------------------------------
// Host-side launch sequence
// ---------------------------------------------------------------------------
extern "C" void kernel_launch(void* const* d_in, const int* in_sizes, int n_in,
                              void* d_out, int out_size, void* d_ws,
                              size_t ws_size, hipStream_t stream) {
  (void)in_sizes; (void)n_in; (void)out_size; (void)ws_size;
  const float* u_in = (const float*)d_in[0];
  const int*   v_in = (const int*)d_in[1];
  const float* emb  = (const float*)d_in[2];
  const float* w1   = (const float*)d_in[3];
  const float* b1   = (const float*)d_in[4];
  const float* w2   = (const float*)d_in[5];
  const float* b2   = (const float*)d_in[6];
  const float* wih  = (const float*)d_in[7];
  const float* whh  = (const float*)d_in[8];
  const float* bih  = (const float*)d_in[9];
  const float* bhh  = (const float*)d_in[10];

  float* ws = (float*)d_ws;
  const size_t HP = (size_t)4 * NB * NC;
  float* h0buf = ws;                               // [2][4][NB][NC]
  float* cbuf  = h0buf + 2 * HP;                   // [4][NB][NC]
  float* Hpart = cbuf + HP;                        // [8][NB][NC]
  float* WDp   = Hpart + (size_t)8 * NB * NC;      // [15][NC]
  float* A0v   = WDp + NFS * NC;                   // [NC]
  float* u_cur = A0v + NC;                         // [NB][16][16]
  int*   v_cur = (int*)(u_cur + NB * NL * NL);     // [NB][16][16]

  float* out_soft = (float*)d_out;                 // [NB][16][16][2]
  float* out_u = out_soft + NB * NL * NL * 2;      // [NB][16][16]
  float* out_v = out_u + NB * NL * NL;             // [NB][16][16]

  setup_kernel<<<dim3(4096), dim3(256), 0, stream>>>(
      u_in, v_in, h0buf, cbuf, u_cur, v_cur, out_soft, out_u, out_v);
  wd_kernel<<<dim3(16), dim3(256), 0, stream>>>(emb, w1, b1, WDp, A0v);

  for (int k = 0; k < 9; k++) {
    if (k > 0) {
      int e = k - 1;
      int col0 = (e % 3 == 0) ? 4 : ((e % 3 == 1) ? 8 : 0);
      lstm_event_kernel<<<dim3(384), dim3(256), 0, stream>>>(
          u_cur, whh, wih, bih, bhh,
          h0buf + (size_t)(e & 1) * HP,
          h0buf + (size_t)((e & 1) ^ 1) * HP, cbuf, col0);
    }
    w1h0_kernel<<<dim3(256), dim3(256), 0, stream>>>(
        h0buf + (size_t)(k & 1) * HP + (size_t)(k / 3) * NB * NC, w1, Hpart);
    pixel_kernel<<<dim3(256), dim3(64), 0, stream>>>(
        WDp, A0v, Hpart, w2, b2, u_cur, v_cur, out_soft, out_u, out_v,
        (k / 3) * 4, (k % 3) * 4, k * 16);
  }
}